// Round 1
// baseline (6715.781 us; speedup 1.0000x reference)
//
#include <hip/hip_runtime.h>

typedef _Float16 half8 __attribute__((ext_vector_type(8)));
typedef float f32x4 __attribute__((ext_vector_type(4)));

#define IN_F 4096
#define OUT_F 4096
#define NBLK 64
#define BIN 512
#define BOUT 512

#define BM 128
#define BN 256
#define BK 64

// Detect whether index arrays arrived as int64 (odd 32-bit words all zero) or int32.
__global__ void detect_stride_k(const int* __restrict__ iin, int* __restrict__ flag) {
    int v = iin[threadIdx.x * 2 + 1];
    unsigned long long b = __ballot(v != 0);
    if (threadIdx.x == 0) flag[0] = (b == 0ULL) ? 2 : 1;
}

// out[b,s,:] = bias  (float4-vectorized)
__global__ void init_bias_k(const float* __restrict__ bias, float* __restrict__ out) {
    int i = blockIdx.x * blockDim.x + threadIdx.x;   // float4 index
    f32x4 b = *(const f32x4*)(bias + ((i & 1023) << 2));
    *(f32x4*)(out + (size_t)i * 4) = b;
}

__global__ __launch_bounds__(512) void block_gemm_k(
    const float* __restrict__ x, const float* __restrict__ w,
    const int* __restrict__ iin, const int* __restrict__ iout,
    const int* __restrict__ flag, float* __restrict__ out)
{
    __shared__ _Float16 As[BM * BK];   // 16 KiB, XOR-swizzled rows
    __shared__ _Float16 Bs[BN * BK];   // 32 KiB, XOR-swizzled rows
    __shared__ int kidx[BIN];
    __shared__ int oidx[BN];

    const int t  = threadIdx.x;
    const int mt = blockIdx.x, nt = blockIdx.y, n = blockIdx.z;
    const int m0 = mt * BM;
    const int stride = flag[0];

    kidx[t] = iin[(n * BIN + t) * stride];
    if (t < BN) oidx[t] = iout[(n * BOUT + nt * BN + t) * stride];
    __syncthreads();

    const int lane = t & 63, wid = t >> 6;
    const int wr = wid >> 2, wc = wid & 3;       // 2 x 4 waves, 64x64 each
    const int lr = lane & 15, lh = lane >> 4;

    f32x4 acc[4][4];
    #pragma unroll
    for (int i = 0; i < 4; ++i)
        #pragma unroll
        for (int j = 0; j < 4; ++j) acc[i][j] = (f32x4){0.f, 0.f, 0.f, 0.f};

    char* Asb = (char*)As;
    char* Bsb = (char*)Bs;

    for (int k0 = 0; k0 < BIN; k0 += BK) {
        // ---- stage A: gathered columns of x, f32 -> f16, swizzled LDS ----
        #pragma unroll
        for (int rep = 0; rep < 2; ++rep) {
            int q = t + rep * 512;
            int m = q >> 3, s = q & 7;           // m: 0..127, s: 16B slot 0..7
            const int4 ia = *(const int4*)&kidx[k0 + s * 8];
            const int4 ib = *(const int4*)&kidx[k0 + s * 8 + 4];
            const float* xr = x + (size_t)(m0 + m) * IN_F;
            half8 p;
            p[0] = (_Float16)xr[ia.x]; p[1] = (_Float16)xr[ia.y];
            p[2] = (_Float16)xr[ia.z]; p[3] = (_Float16)xr[ia.w];
            p[4] = (_Float16)xr[ib.x]; p[5] = (_Float16)xr[ib.y];
            p[6] = (_Float16)xr[ib.z]; p[7] = (_Float16)xr[ib.w];
            *(half8*)(Asb + m * (BK * 2) + ((s * 16) ^ ((m & 7) << 4))) = p;
        }
        // ---- stage B: dense rows of W (already [out][in] = B^T), f32 -> f16 ----
        #pragma unroll
        for (int rep = 0; rep < 4; ++rep) {
            int q = t + rep * 512;
            int o = q >> 3, s = q & 7;           // o: 0..255
            const float* wrow = w + ((size_t)n * BOUT + nt * BN + o) * BIN + k0 + s * 8;
            f32x4 w0 = *(const f32x4*)wrow;
            f32x4 w1 = *(const f32x4*)(wrow + 4);
            half8 p;
            p[0] = (_Float16)w0[0]; p[1] = (_Float16)w0[1];
            p[2] = (_Float16)w0[2]; p[3] = (_Float16)w0[3];
            p[4] = (_Float16)w1[0]; p[5] = (_Float16)w1[1];
            p[6] = (_Float16)w1[2]; p[7] = (_Float16)w1[3];
            *(half8*)(Bsb + o * (BK * 2) + ((s * 16) ^ ((o & 7) << 4))) = p;
        }
        __syncthreads();
        // ---- compute: 2 k-chunks x 16 MFMA per wave ----
        #pragma unroll
        for (int kk = 0; kk < 2; ++kk) {
            half8 a[4], b[4];
            #pragma unroll
            for (int fm = 0; fm < 4; ++fm) {
                int m = wr * 64 + fm * 16 + lr;
                a[fm] = *(const half8*)(Asb + m * (BK * 2) +
                                        (((kk * 4 + lh) * 16) ^ ((m & 7) << 4)));
            }
            #pragma unroll
            for (int fn = 0; fn < 4; ++fn) {
                int o = wc * 64 + fn * 16 + lr;
                b[fn] = *(const half8*)(Bsb + o * (BK * 2) +
                                        (((kk * 4 + lh) * 16) ^ ((o & 7) << 4)));
            }
            #pragma unroll
            for (int fm = 0; fm < 4; ++fm)
                #pragma unroll
                for (int fn = 0; fn < 4; ++fn)
                    acc[fm][fn] = __builtin_amdgcn_mfma_f32_16x16x32_f16(
                        a[fm], b[fn], acc[fm][fn], 0, 0, 0);
        }
        __syncthreads();
    }

    // ---- epilogue: scatter-add via global atomics ----
    int ocol[4];
    #pragma unroll
    for (int fn = 0; fn < 4; ++fn) ocol[fn] = oidx[wc * 64 + fn * 16 + lr];
    #pragma unroll
    for (int fm = 0; fm < 4; ++fm) {
        int rbase = m0 + wr * 64 + fm * 16 + lh * 4;
        #pragma unroll
        for (int fn = 0; fn < 4; ++fn) {
            float* op = out + (size_t)rbase * OUT_F + ocol[fn];
            #pragma unroll
            for (int r = 0; r < 4; ++r)
                atomicAdd(op + (size_t)r * OUT_F, acc[fm][fn][r]);
        }
    }
}

extern "C" void kernel_launch(void* const* d_in, const int* in_sizes, int n_in,
                              void* d_out, int out_size, void* d_ws, size_t ws_size,
                              hipStream_t stream) {
    (void)in_sizes; (void)n_in; (void)ws_size;
    const float* x    = (const float*)d_in[0];
    const float* w    = (const float*)d_in[1];
    const float* bias = (const float*)d_in[2];
    const int* iin    = (const int*)d_in[3];
    const int* iout   = (const int*)d_in[4];
    float* out        = (float*)d_out;
    int* flag         = (int*)d_ws;

    detect_stride_k<<<1, 64, 0, stream>>>(iin, flag);
    init_bias_k<<<out_size / 1024, 256, 0, stream>>>(bias, out);
    block_gemm_k<<<dim3(32, 2, 64), 512, 0, stream>>>(x, w, iin, iout, flag, out);
}

// Round 2
// 2662.668 us; speedup vs baseline: 2.5222x; 2.5222x over previous
//
#include <hip/hip_runtime.h>

typedef _Float16 half4 __attribute__((ext_vector_type(4)));
typedef _Float16 half8 __attribute__((ext_vector_type(8)));
typedef float f32x4 __attribute__((ext_vector_type(4)));

#define IN_F 4096
#define OUT_F 4096
#define NROWS 4096   // B*S = 2*2048
#define NBLK 64
#define BIN 512
#define BOUT 512

#define BM 128
#define BN 512
#define BK 32

// Detect whether index arrays arrived as int64 (odd 32-bit words all zero) or int32.
__global__ void detect_stride_k(const int* __restrict__ iin, int* __restrict__ flag) {
    int v = iin[threadIdx.x * 2 + 1];
    unsigned long long b = __ballot(v != 0);
    if (threadIdx.x == 0) flag[0] = (b == 0ULL) ? 2 : 1;
}

// One-time W f32 -> f16 conversion (32 MB workspace).
__global__ void cvt_w16_k(const float* __restrict__ w, _Float16* __restrict__ w16) {
    int i = (blockIdx.x * 256 + threadIdx.x) * 4;
    f32x4 v = *(const f32x4*)(w + i);
    half4 h;
    h[0] = (_Float16)v[0]; h[1] = (_Float16)v[1];
    h[2] = (_Float16)v[2]; h[3] = (_Float16)v[3];
    *(half4*)(w16 + i) = h;
}

// Fallback path only: out[b,s,:] = bias
__global__ void init_bias_k(const float* __restrict__ bias, float* __restrict__ out) {
    int i = blockIdx.x * blockDim.x + threadIdx.x;   // float4 index
    f32x4 b = *(const f32x4*)(bias + ((i & 1023) << 2));
    *(f32x4*)(out + (size_t)i * 4) = b;
}

// MODE 1: epilogue scatters line-coalesced atomics into outT[col][s] (dst = outT), reads w16.
// MODE 0: fallback — direct atomics into out[s][col] (dst = out), reads w f32.
template<int MODE>
__global__ __launch_bounds__(1024) void block_gemm_k(
    const float* __restrict__ x, const float* __restrict__ w,
    const _Float16* __restrict__ w16,
    const int* __restrict__ iin, const int* __restrict__ iout,
    const int* __restrict__ flag, float* __restrict__ dst)
{
    __shared__ _Float16 As[BM * BK];   // 8 KiB, 64B rows, XOR-swizzled
    __shared__ _Float16 Bs[BN * BK];   // 32 KiB
    __shared__ int kidx[BIN];
    __shared__ int oidx[BOUT];

    const int t  = threadIdx.x;
    const int mt = blockIdx.x, n = blockIdx.y;
    const int m0 = mt * BM;
    const int stride = flag[0];

    if (t < BIN) kidx[t] = iin[(n * BIN + t) * stride];
    else         oidx[t - BIN] = iout[(n * BOUT + (t - BIN)) * stride];
    __syncthreads();

    const int lane = t & 63, wid = t >> 6;
    const int wr = wid >> 3, wc = wid & 7;       // 2 x 8 waves, 64x64 tile each
    const int lr = lane & 15, lh = lane >> 4;

    f32x4 acc[4][4];
    #pragma unroll
    for (int i = 0; i < 4; ++i)
        #pragma unroll
        for (int j = 0; j < 4; ++j) acc[i][j] = (f32x4){0.f, 0.f, 0.f, 0.f};

    char* Asb = (char*)As;
    char* Bsb = (char*)Bs;

    for (int k0 = 0; k0 < BIN; k0 += BK) {
        // ---- stage A: gathered columns of x, f32 -> f16 (4 scalars / thread) ----
        {
            int m = t >> 3, c4 = (t & 7) * 4;
            const float* xr = x + (size_t)(m0 + m) * IN_F;
            int i0 = kidx[k0 + c4 + 0], i1 = kidx[k0 + c4 + 1];
            int i2 = kidx[k0 + c4 + 2], i3 = kidx[k0 + c4 + 3];
            half4 p;
            p[0] = (_Float16)xr[i0]; p[1] = (_Float16)xr[i1];
            p[2] = (_Float16)xr[i2]; p[3] = (_Float16)xr[i3];
            *(half4*)(Asb + m * 64 + ((c4 * 2) ^ (((m >> 1) & 3) << 4))) = p;
        }
        // ---- stage B: dense rows of W (already [o][k] = B^T), 32B / thread ----
        {
            int o = t >> 1, h = t & 1;
            int sw = ((o >> 1) & 3) << 4;
            char* db = Bsb + o * 64;
            if (MODE) {
                const _Float16* src = w16 + ((size_t)n * BOUT + o) * BIN + k0 + h * 16;
                *(half8*)(db + ((h * 32)      ^ sw)) = *(const half8*)src;
                *(half8*)(db + ((h * 32 + 16) ^ sw)) = *(const half8*)(src + 8);
            } else {
                const float* src = w + ((size_t)n * BOUT + o) * BIN + k0 + h * 16;
                f32x4 a0 = *(const f32x4*)src;
                f32x4 a1 = *(const f32x4*)(src + 4);
                f32x4 a2 = *(const f32x4*)(src + 8);
                f32x4 a3 = *(const f32x4*)(src + 12);
                half8 p0, p1;
                p0[0] = (_Float16)a0[0]; p0[1] = (_Float16)a0[1];
                p0[2] = (_Float16)a0[2]; p0[3] = (_Float16)a0[3];
                p0[4] = (_Float16)a1[0]; p0[5] = (_Float16)a1[1];
                p0[6] = (_Float16)a1[2]; p0[7] = (_Float16)a1[3];
                p1[0] = (_Float16)a2[0]; p1[1] = (_Float16)a2[1];
                p1[2] = (_Float16)a2[2]; p1[3] = (_Float16)a2[3];
                p1[4] = (_Float16)a3[0]; p1[5] = (_Float16)a3[1];
                p1[6] = (_Float16)a3[2]; p1[7] = (_Float16)a3[3];
                *(half8*)(db + ((h * 32)      ^ sw)) = p0;
                *(half8*)(db + ((h * 32 + 16) ^ sw)) = p1;
            }
        }
        __syncthreads();
        // ---- compute: 16 MFMA per wave per k-step ----
        {
            half8 a[4], b[4];
            #pragma unroll
            for (int fm = 0; fm < 4; ++fm) {
                int m = wr * 64 + fm * 16 + lr;
                a[fm] = *(const half8*)(Asb + m * 64 + ((lh * 16) ^ (((m >> 1) & 3) << 4)));
            }
            #pragma unroll
            for (int fn = 0; fn < 4; ++fn) {
                int o = wc * 64 + fn * 16 + lr;
                b[fn] = *(const half8*)(Bsb + o * 64 + ((lh * 16) ^ (((o >> 1) & 3) << 4)));
            }
            #pragma unroll
            for (int fm = 0; fm < 4; ++fm)
                #pragma unroll
                for (int fn = 0; fn < 4; ++fn)
                    acc[fm][fn] = __builtin_amdgcn_mfma_f32_16x16x32_f16(
                        a[fm], b[fn], acc[fm][fn], 0, 0, 0);
        }
        __syncthreads();
    }

    // ---- epilogue: scatter-add ----
    int ocol[4];
    #pragma unroll
    for (int fn = 0; fn < 4; ++fn) ocol[fn] = oidx[wc * 64 + fn * 16 + lr];

    if (MODE) {
        // outT[col][s]: lanes {c,c+16,c+32,c+48} x regs 0..3 cover 16 consecutive s
        // -> one 64B line per (col, s16-group). Line-coalesced atomics.
        #pragma unroll
        for (int fm = 0; fm < 4; ++fm) {
            int sbase = m0 + wr * 64 + fm * 16 + lh * 4;
            #pragma unroll
            for (int fn = 0; fn < 4; ++fn) {
                float* op = dst + (size_t)ocol[fn] * NROWS + sbase;
                #pragma unroll
                for (int r = 0; r < 4; ++r)
                    atomicAdd(op + r, acc[fm][fn][r]);
            }
        }
    } else {
        #pragma unroll
        for (int fm = 0; fm < 4; ++fm) {
            int rbase = m0 + wr * 64 + fm * 16 + lh * 4;
            #pragma unroll
            for (int fn = 0; fn < 4; ++fn) {
                float* op = dst + (size_t)rbase * OUT_F + ocol[fn];
                #pragma unroll
                for (int r = 0; r < 4; ++r)
                    atomicAdd(op + (size_t)r * OUT_F, acc[fm][fn][r]);
            }
        }
    }
}

// out[s][col] = outT[col][s] + bias[col]  (64x64 LDS tiles, both sides coalesced)
__global__ __launch_bounds__(256) void transpose_bias_k(
    const float* __restrict__ outT, const float* __restrict__ bias,
    float* __restrict__ out)
{
    __shared__ float tile[64][65];
    const int c0 = blockIdx.x * 64, s0 = blockIdx.y * 64;
    const int t = threadIdx.x;

    {
        int sl = (t & 15) * 4, cl = t >> 4;
        #pragma unroll
        for (int j = 0; j < 4; ++j) {
            int c = cl + j * 16;
            f32x4 v = *(const f32x4*)(outT + (size_t)(c0 + c) * NROWS + s0 + sl);
            tile[c][sl + 0] = v[0]; tile[c][sl + 1] = v[1];
            tile[c][sl + 2] = v[2]; tile[c][sl + 3] = v[3];
        }
    }
    __syncthreads();
    {
        int c4 = (t & 15) * 4, s = t >> 4;
        f32x4 bb = *(const f32x4*)(bias + c0 + c4);
        #pragma unroll
        for (int j = 0; j < 4; ++j) {
            int ss = s + j * 16;
            f32x4 v;
            v[0] = tile[c4 + 0][ss]; v[1] = tile[c4 + 1][ss];
            v[2] = tile[c4 + 2][ss]; v[3] = tile[c4 + 3][ss];
            v += bb;
            *(f32x4*)(out + (size_t)(s0 + ss) * OUT_F + c0 + c4) = v;
        }
    }
}

extern "C" void kernel_launch(void* const* d_in, const int* in_sizes, int n_in,
                              void* d_out, int out_size, void* d_ws, size_t ws_size,
                              hipStream_t stream) {
    (void)in_sizes; (void)n_in;
    const float* x    = (const float*)d_in[0];
    const float* w    = (const float*)d_in[1];
    const float* bias = (const float*)d_in[2];
    const int* iin    = (const int*)d_in[3];
    const int* iout   = (const int*)d_in[4];
    float* out        = (float*)d_out;

    const size_t outT_bytes = (size_t)OUT_F * NROWS * 4;          // 64 MiB
    const size_t w16_bytes  = (size_t)NBLK * BOUT * BIN * 2;      // 32 MiB
    const bool big = ws_size >= outT_bytes + w16_bytes + 256;

    if (big) {
        float*     outT = (float*)d_ws;
        _Float16*  w16  = (_Float16*)((char*)d_ws + outT_bytes);
        int*       flag = (int*)((char*)d_ws + outT_bytes + w16_bytes);
        detect_stride_k<<<1, 64, 0, stream>>>(iin, flag);
        cvt_w16_k<<<(NBLK * BOUT * BIN) / 1024, 256, 0, stream>>>(w, w16);
        hipMemsetAsync(d_ws, 0, outT_bytes, stream);
        block_gemm_k<1><<<dim3(NROWS / BM, NBLK), 1024, 0, stream>>>(
            x, w, w16, iin, iout, flag, outT);
        transpose_bias_k<<<dim3(OUT_F / 64, NROWS / 64), 256, 0, stream>>>(outT, bias, out);
    } else {
        int* flag = (int*)d_ws;
        detect_stride_k<<<1, 64, 0, stream>>>(iin, flag);
        init_bias_k<<<out_size / 1024, 256, 0, stream>>>(bias, out);
        block_gemm_k<0><<<dim3(NROWS / BM, NBLK), 1024, 0, stream>>>(
            x, w, nullptr, iin, iout, flag, out);
    }
}

// Round 3
// 1180.193 us; speedup vs baseline: 5.6904x; 2.2561x over previous
//
#include <hip/hip_runtime.h>

typedef _Float16 half8 __attribute__((ext_vector_type(8)));
typedef _Float16 half4 __attribute__((ext_vector_type(4)));
typedef float f32x4 __attribute__((ext_vector_type(4)));

#define IN_F 4096
#define OUT_F 4096
#define NROWS 4096   // B*S
#define NBLK 64
#define BIN 512
#define BOUT 512
#define NC 8         // n-blocks per chunk

#define BM 128
#define BN 512
#define BK 32

__device__ __forceinline__ void gload16(const void* g, void* l) {
    typedef __attribute__((address_space(1))) const void gvoid;
    typedef __attribute__((address_space(3))) void lvoid;
    __builtin_amdgcn_global_load_lds((gvoid*)g, (lvoid*)l, 16, 0, 0);
}

// int64 vs int32 index detection
__global__ void detect_stride_k(const int* __restrict__ iin, int* __restrict__ flag) {
    int v = iin[threadIdx.x * 2 + 1];
    unsigned long long b = __ballot(v != 0);
    if (threadIdx.x == 0) flag[0] = (b == 0ULL) ? 2 : 1;
}

// W f32 -> f16 (once)
__global__ void cvt_w16_k(const float* __restrict__ w, _Float16* __restrict__ w16) {
    int i = (blockIdx.x * 256 + threadIdx.x) * 4;
    f32x4 v = *(const f32x4*)(w + i);
    half4 h;
    h[0] = (_Float16)v[0]; h[1] = (_Float16)v[1];
    h[2] = (_Float16)v[2]; h[3] = (_Float16)v[3];
    *(half4*)(w16 + i) = h;
}

// x[s][c] f32 -> xT16[c][s] f16
__global__ __launch_bounds__(256) void transpose_x_k(
    const float* __restrict__ x, _Float16* __restrict__ xT16)
{
    __shared__ float tile[64][65];
    const int c0 = blockIdx.x * 64, s0 = blockIdx.y * 64;
    const int t = threadIdx.x;
    {
        int s = t >> 4, c4 = (t & 15) * 4;
        #pragma unroll
        for (int p = 0; p < 4; ++p) {
            int ss = s + p * 16;
            f32x4 v = *(const f32x4*)(x + (size_t)(s0 + ss) * IN_F + c0 + c4);
            tile[ss][c4 + 0] = v[0]; tile[ss][c4 + 1] = v[1];
            tile[ss][c4 + 2] = v[2]; tile[ss][c4 + 3] = v[3];
        }
    }
    __syncthreads();
    {
        int c = t >> 3, s8 = (t & 7) * 8;
        #pragma unroll
        for (int p = 0; p < 2; ++p) {
            int cc = c + p * 32;
            half8 v;
            #pragma unroll
            for (int q = 0; q < 8; ++q) v[q] = (_Float16)tile[s8 + q][cc];
            *(half8*)(xT16 + (size_t)(c0 + cc) * NROWS + s0 + s8) = v;
        }
    }
}

// outT[c][s] = (f16)bias[c]
__global__ void fill_biasT_k(const float* __restrict__ bias, _Float16* __restrict__ outT) {
    size_t i = (size_t)blockIdx.x * 256 + threadIdx.x;   // half8 index
    int c = (int)(i >> 9);
    _Float16 b = (_Float16)bias[c];
    half8 v = {b, b, b, b, b, b, b, b};
    *(half8*)(outT + i * 8) = v;
}

// xg16[nl][s][j] = xT16[kidx[n][j]][s]  (gather + transpose, chunk of NC blocks)
__global__ __launch_bounds__(256) void gather_k(
    const _Float16* __restrict__ xT16, const int* __restrict__ iin,
    const int* __restrict__ flag, int chunk, _Float16* __restrict__ xg16)
{
    __shared__ _Float16 tile[64][264];
    __shared__ int cidx[64];
    const int t = threadIdx.x;
    const int j0 = blockIdx.x * 64;
    const int s0 = blockIdx.y * 256;
    const int nl = blockIdx.z;
    const int n = chunk * NC + nl;
    if (t < 64) cidx[t] = iin[((size_t)n * BIN + j0 + t) * flag[0]];
    __syncthreads();
    {
        int j = t >> 5, u = t & 31;
        #pragma unroll
        for (int p = 0; p < 8; ++p) {
            int jj = j + p * 8;
            half8 v = *(const half8*)(xT16 + (size_t)cidx[jj] * NROWS + s0 + u * 8);
            *(half8*)&tile[jj][u * 8] = v;
        }
    }
    __syncthreads();
    {
        int s = t >> 3, jj8 = (t & 7) * 8;
        #pragma unroll
        for (int p = 0; p < 8; ++p) {
            int ss = s + p * 32;
            half8 v;
            #pragma unroll
            for (int q = 0; q < 8; ++q) v[q] = tile[jj8 + q][ss];
            *(half8*)(xg16 + ((size_t)nl * NROWS + s0 + ss) * BIN + j0 + jj8) = v;
        }
    }
}

// dense f16 GEMM per (mt, nl), atomic pk-f16 scatter into outT[col][s]
__global__ __launch_bounds__(1024) void gemm_fast_k(
    const _Float16* __restrict__ xg16, const _Float16* __restrict__ w16,
    const int* __restrict__ iout, const int* __restrict__ flag,
    int chunk, _Float16* __restrict__ outT)
{
    __shared__ __align__(1024) _Float16 As[2][BM * BK];   // 2 x 8 KiB
    __shared__ __align__(1024) _Float16 Bs[2][BN * BK];   // 2 x 32 KiB
    __shared__ int oidx[BOUT];

    const int t = threadIdx.x;
    const int bid = blockIdx.x;
    const int nl = bid & 7, mt = bid >> 3;    // XCD = bid%8 -> one n per XCD
    const int n = chunk * NC + nl;
    const int m0 = mt * BM;

    if (t < BOUT) oidx[t] = iout[((size_t)n * BOUT + t) * flag[0]];

    const int lane = t & 63, wid = t >> 6;
    char* Asb = (char*)As;
    char* Bsb = (char*)Bs;

    auto STAGE = [&](int buf, int k0) {
        int ml = lane >> 2, sl = lane & 3;
        if (wid < 8) {
            int m = (wid << 4) + ml;
            const char* src = (const char*)(xg16 + ((size_t)nl * NROWS + m0 + m) * BIN + k0)
                              + (((sl << 4)) ^ (((m >> 1) & 3) << 4));
            gload16(src, Asb + buf * (BM * BK * 2) + (wid << 10));
        }
        int o = (wid << 5) + ml;
        const char* sB = (const char*)(w16 + ((size_t)n * BOUT + o) * BIN + k0)
                         + (((sl << 4)) ^ (((o >> 1) & 3) << 4));
        gload16(sB, Bsb + buf * (BN * BK * 2) + (wid << 11));
        int o2 = o + 16;
        const char* sB2 = (const char*)(w16 + ((size_t)n * BOUT + o2) * BIN + k0)
                          + (((sl << 4)) ^ (((o2 >> 1) & 3) << 4));
        gload16(sB2, Bsb + buf * (BN * BK * 2) + (wid << 11) + 1024);
    };

    f32x4 acc[4][4];
    #pragma unroll
    for (int i = 0; i < 4; ++i)
        #pragma unroll
        for (int j = 0; j < 4; ++j) acc[i][j] = (f32x4){0.f, 0.f, 0.f, 0.f};

    STAGE(0, 0);
    __syncthreads();

    const int wr = wid >> 3, wc = wid & 7;    // 2 x 8 waves, 64x64 each
    const int lr = lane & 15, lh = lane >> 4;

    for (int ks = 0; ks < 16; ++ks) {
        const int cur = ks & 1;
        if (ks < 15) STAGE(cur ^ 1, (ks + 1) * BK);
        half8 a[4], b[4];
        #pragma unroll
        for (int fm = 0; fm < 4; ++fm) {
            int m = wr * 64 + fm * 16 + lr;
            a[fm] = *(const half8*)(Asb + cur * (BM * BK * 2) + m * 64 +
                                    ((lh << 4) ^ (((m >> 1) & 3) << 4)));
        }
        #pragma unroll
        for (int fn = 0; fn < 4; ++fn) {
            int o = wc * 64 + fn * 16 + lr;
            b[fn] = *(const half8*)(Bsb + cur * (BN * BK * 2) + o * 64 +
                                    ((lh << 4) ^ (((o >> 1) & 3) << 4)));
        }
        #pragma unroll
        for (int fm = 0; fm < 4; ++fm)
            #pragma unroll
            for (int fn = 0; fn < 4; ++fn)
                acc[fm][fn] = __builtin_amdgcn_mfma_f32_16x16x32_f16(
                    a[fm], b[fn], acc[fm][fn], 0, 0, 0);
        __syncthreads();
    }

    int ocol[4];
    #pragma unroll
    for (int fn = 0; fn < 4; ++fn) ocol[fn] = oidx[wc * 64 + fn * 16 + lr];
    #pragma unroll
    for (int fm = 0; fm < 4; ++fm) {
        int sbase = m0 + wr * 64 + fm * 16 + lh * 4;
        #pragma unroll
        for (int fn = 0; fn < 4; ++fn) {
            _Float16* op = outT + (size_t)ocol[fn] * NROWS + sbase;
            #pragma unroll
            for (int rp = 0; rp < 2; ++rp) {
                union { _Float16 h[2]; unsigned u; } d;
                d.h[0] = (_Float16)acc[fm][fn][2 * rp];
                d.h[1] = (_Float16)acc[fm][fn][2 * rp + 1];
                asm volatile("global_atomic_pk_add_f16 %0, %1, off"
                             :: "v"(op + 2 * rp), "v"(d.u) : "memory");
            }
        }
    }
}

// out[s][c] = (f32)outT[c][s]   (reads full 64B line per col, lane-contiguous stores)
__global__ __launch_bounds__(256) void untranspose_k(
    const _Float16* __restrict__ outT, float* __restrict__ out)
{
    const int c = blockIdx.x * 256 + threadIdx.x;
    const int S0 = blockIdx.y * 32;
    half8 v[4];
    #pragma unroll
    for (int q = 0; q < 4; ++q)
        v[q] = *(const half8*)(outT + (size_t)c * NROWS + S0 + q * 8);
    #pragma unroll
    for (int q = 0; q < 4; ++q)
        #pragma unroll
        for (int r = 0; r < 8; ++r)
            out[(size_t)(S0 + q * 8 + r) * OUT_F + c] = (float)v[q][r];
}

// ---------------- fallback path (tiny ws): direct atomics into out ----------------
__global__ void init_bias_k(const float* __restrict__ bias, float* __restrict__ out) {
    int i = blockIdx.x * blockDim.x + threadIdx.x;
    f32x4 b = *(const f32x4*)(bias + ((i & 1023) << 2));
    *(f32x4*)(out + (size_t)i * 4) = b;
}

__global__ __launch_bounds__(1024) void gemm_slow_k(
    const float* __restrict__ x, const float* __restrict__ w,
    const int* __restrict__ iin, const int* __restrict__ iout,
    const int* __restrict__ flag, float* __restrict__ out)
{
    __shared__ _Float16 As[BM * BK];
    __shared__ _Float16 Bs[BN * BK];
    __shared__ int kidx[BIN];
    __shared__ int oidx[BOUT];

    const int t = threadIdx.x;
    const int mt = blockIdx.x, n = blockIdx.y;
    const int m0 = mt * BM;
    const int stride = flag[0];

    if (t < BIN) kidx[t] = iin[(n * BIN + t) * stride];
    else         oidx[t - BIN] = iout[(n * BOUT + (t - BIN)) * stride];
    __syncthreads();

    const int lane = t & 63, wid = t >> 6;
    const int wr = wid >> 3, wc = wid & 7;
    const int lr = lane & 15, lh = lane >> 4;

    f32x4 acc[4][4];
    #pragma unroll
    for (int i = 0; i < 4; ++i)
        #pragma unroll
        for (int j = 0; j < 4; ++j) acc[i][j] = (f32x4){0.f, 0.f, 0.f, 0.f};

    char* Asb = (char*)As;
    char* Bsb = (char*)Bs;

    for (int k0 = 0; k0 < BIN; k0 += BK) {
        {
            int m = t >> 3, c4 = (t & 7) * 4;
            const float* xr = x + (size_t)(m0 + m) * IN_F;
            int i0 = kidx[k0 + c4], i1 = kidx[k0 + c4 + 1];
            int i2 = kidx[k0 + c4 + 2], i3 = kidx[k0 + c4 + 3];
            half4 p;
            p[0] = (_Float16)xr[i0]; p[1] = (_Float16)xr[i1];
            p[2] = (_Float16)xr[i2]; p[3] = (_Float16)xr[i3];
            *(half4*)(Asb + m * 64 + ((c4 * 2) ^ (((m >> 1) & 3) << 4))) = p;
        }
        {
            int o = t >> 1, h = t & 1;
            int sw = ((o >> 1) & 3) << 4;
            char* db = Bsb + o * 64;
            const float* src = w + ((size_t)n * BOUT + o) * BIN + k0 + h * 16;
            f32x4 a0 = *(const f32x4*)src;
            f32x4 a1 = *(const f32x4*)(src + 4);
            f32x4 a2 = *(const f32x4*)(src + 8);
            f32x4 a3 = *(const f32x4*)(src + 12);
            half8 p0, p1;
            p0[0] = (_Float16)a0[0]; p0[1] = (_Float16)a0[1];
            p0[2] = (_Float16)a0[2]; p0[3] = (_Float16)a0[3];
            p0[4] = (_Float16)a1[0]; p0[5] = (_Float16)a1[1];
            p0[6] = (_Float16)a1[2]; p0[7] = (_Float16)a1[3];
            p1[0] = (_Float16)a2[0]; p1[1] = (_Float16)a2[1];
            p1[2] = (_Float16)a2[2]; p1[3] = (_Float16)a2[3];
            p1[4] = (_Float16)a3[0]; p1[5] = (_Float16)a3[1];
            p1[6] = (_Float16)a3[2]; p1[7] = (_Float16)a3[3];
            *(half8*)(db + ((h * 32) ^ sw)) = p0;
            *(half8*)(db + ((h * 32 + 16) ^ sw)) = p1;
        }
        __syncthreads();
        {
            half8 a[4], b[4];
            #pragma unroll
            for (int fm = 0; fm < 4; ++fm) {
                int m = wr * 64 + fm * 16 + lr;
                a[fm] = *(const half8*)(Asb + m * 64 + ((lh * 16) ^ (((m >> 1) & 3) << 4)));
            }
            #pragma unroll
            for (int fn = 0; fn < 4; ++fn) {
                int o = wc * 64 + fn * 16 + lr;
                b[fn] = *(const half8*)(Bsb + o * 64 + ((lh * 16) ^ (((o >> 1) & 3) << 4)));
            }
            #pragma unroll
            for (int fm = 0; fm < 4; ++fm)
                #pragma unroll
                for (int fn = 0; fn < 4; ++fn)
                    acc[fm][fn] = __builtin_amdgcn_mfma_f32_16x16x32_f16(
                        a[fm], b[fn], acc[fm][fn], 0, 0, 0);
        }
        __syncthreads();
    }

    int ocol[4];
    #pragma unroll
    for (int fn = 0; fn < 4; ++fn) ocol[fn] = oidx[wc * 64 + fn * 16 + lr];
    #pragma unroll
    for (int fm = 0; fm < 4; ++fm) {
        int rbase = m0 + wr * 64 + fm * 16 + lh * 4;
        #pragma unroll
        for (int fn = 0; fn < 4; ++fn) {
            float* op = out + (size_t)rbase * OUT_F + ocol[fn];
            #pragma unroll
            for (int r = 0; r < 4; ++r)
                atomicAdd(op + (size_t)r * OUT_F, acc[fm][fn][r]);
        }
    }
}

extern "C" void kernel_launch(void* const* d_in, const int* in_sizes, int n_in,
                              void* d_out, int out_size, void* d_ws, size_t ws_size,
                              hipStream_t stream) {
    (void)in_sizes; (void)n_in; (void)out_size;
    const float* x    = (const float*)d_in[0];
    const float* w    = (const float*)d_in[1];
    const float* bias = (const float*)d_in[2];
    const int* iin    = (const int*)d_in[3];
    const int* iout   = (const int*)d_in[4];
    float* out        = (float*)d_out;

    const size_t MB32 = 32u * 1024u * 1024u;
    const size_t need = 4 * MB32 + 256;      // outT16 + w16 + xT16 + xg16 + flag

    if (ws_size >= need) {
        _Float16* outT = (_Float16*)d_ws;                          // 32 MiB
        _Float16* w16  = (_Float16*)((char*)d_ws + MB32);          // 32 MiB
        _Float16* xT16 = (_Float16*)((char*)d_ws + 2 * MB32);      // 32 MiB
        _Float16* xg16 = (_Float16*)((char*)d_ws + 3 * MB32);      // 32 MiB (NC=8 chunk)
        int*      flag = (int*)((char*)d_ws + 4 * MB32);

        detect_stride_k<<<1, 64, 0, stream>>>(iin, flag);
        cvt_w16_k<<<(NBLK * BOUT * BIN) / 1024, 256, 0, stream>>>(w, w16);
        transpose_x_k<<<dim3(IN_F / 64, NROWS / 64), 256, 0, stream>>>(x, xT16);
        fill_biasT_k<<<(OUT_F * NROWS / 8) / 256, 256, 0, stream>>>(bias, outT);

        for (int chunk = 0; chunk < NBLK / NC; ++chunk) {
            gather_k<<<dim3(BIN / 64, NROWS / 256, NC), 256, 0, stream>>>(
                xT16, iin, flag, chunk, xg16);
            gemm_fast_k<<<dim3((NROWS / BM) * NC), 1024, 0, stream>>>(
                xg16, w16, iout, flag, chunk, outT);
        }
        untranspose_k<<<dim3(OUT_F / 256, NROWS / 32), 256, 0, stream>>>(outT, out);
    } else {
        int* flag = (int*)d_ws;
        detect_stride_k<<<1, 64, 0, stream>>>(iin, flag);
        init_bias_k<<<(size_t)NROWS * OUT_F / 1024, 256, 0, stream>>>(bias, out);
        gemm_slow_k<<<dim3(NROWS / BM, NBLK), 1024, 0, stream>>>(
            x, w, iin, iout, flag, out);
    }
}

// Round 4
// 585.778 us; speedup vs baseline: 11.4647x; 2.0147x over previous
//
#include <hip/hip_runtime.h>

typedef _Float16 half8 __attribute__((ext_vector_type(8)));
typedef _Float16 half4 __attribute__((ext_vector_type(4)));
typedef float f32x4 __attribute__((ext_vector_type(4)));

#define IN_F 4096
#define OUT_F 4096
#define NROWS 4096   // B*S
#define NBLK 64
#define BIN 512
#define BOUT 512
#define NPAIR (NBLK * BOUT)   // 32768 (n,o) pairs

__device__ __forceinline__ void gload16(const void* g, void* l) {
    typedef __attribute__((address_space(1))) const void gvoid;
    typedef __attribute__((address_space(3))) void lvoid;
    __builtin_amdgcn_global_load_lds((gvoid*)g, (lvoid*)l, 16, 0, 0);
}

// ---------- setup kernels ----------

// int64 vs int32 index detection
__global__ void detect_stride_k(const int* __restrict__ iin, int* __restrict__ flag) {
    int v = iin[threadIdx.x * 2 + 1];
    unsigned long long b = __ballot(v != 0);
    if (threadIdx.x == 0) flag[0] = (b == 0ULL) ? 2 : 1;
}

// W f32 -> f16 (once)
__global__ void cvt_w16_k(const float* __restrict__ w, _Float16* __restrict__ w16) {
    int i = (blockIdx.x * 256 + threadIdx.x) * 4;
    f32x4 v = *(const f32x4*)(w + i);
    half4 h;
    h[0] = (_Float16)v[0]; h[1] = (_Float16)v[1];
    h[2] = (_Float16)v[2]; h[3] = (_Float16)v[3];
    *(half4*)(w16 + i) = h;
}

// x[s][c] f32 -> xT16[c][s] f16
__global__ __launch_bounds__(256) void transpose_x_k(
    const float* __restrict__ x, _Float16* __restrict__ xT16)
{
    __shared__ float tile[64][65];
    const int c0 = blockIdx.x * 64, s0 = blockIdx.y * 64;
    const int t = threadIdx.x;
    {
        int s = t >> 4, c4 = (t & 15) * 4;
        #pragma unroll
        for (int p = 0; p < 4; ++p) {
            int ss = s + p * 16;
            f32x4 v = *(const f32x4*)(x + (size_t)(s0 + ss) * IN_F + c0 + c4);
            tile[ss][c4 + 0] = v[0]; tile[ss][c4 + 1] = v[1];
            tile[ss][c4 + 2] = v[2]; tile[ss][c4 + 3] = v[3];
        }
    }
    __syncthreads();
    {
        int c = t >> 3, s8 = (t & 7) * 8;
        #pragma unroll
        for (int p = 0; p < 2; ++p) {
            int cc = c + p * 32;
            half8 v;
            #pragma unroll
            for (int q = 0; q < 8; ++q) v[q] = (_Float16)tile[s8 + q][cc];
            *(half8*)(xT16 + (size_t)(c0 + cc) * NROWS + s0 + s8) = v;
        }
    }
}

// ---------- inverse-index build ----------

__global__ void count_k(const int* __restrict__ iout, const int* __restrict__ flag,
                        int* __restrict__ cnt) {
    int i = blockIdx.x * 256 + threadIdx.x;      // 32768 threads
    int c = iout[(size_t)i * flag[0]];
    atomicAdd(&cnt[c], 1);
}

// exclusive scan of cnt[4096] -> off[4097], cur[4096]=off  (single block, 256 thr)
__global__ __launch_bounds__(256) void scan_k(const int* __restrict__ cnt,
                                              int* __restrict__ off, int* __restrict__ cur) {
    __shared__ int sums[256];
    const int t = threadIdx.x;
    const int base = t * 16;
    int loc[16];
    int s = 0;
    #pragma unroll
    for (int i = 0; i < 16; ++i) { loc[i] = s; s += cnt[base + i]; }
    sums[t] = s;
    __syncthreads();
    for (int d = 1; d < 256; d <<= 1) {
        int v = (t >= d) ? sums[t - d] : 0;
        __syncthreads();
        sums[t] += v;
        __syncthreads();
    }
    int excl = sums[t] - s;
    #pragma unroll
    for (int i = 0; i < 16; ++i) {
        int o = excl + loc[i];
        off[base + i] = o;
        cur[base + i] = o;
    }
    if (t == 255) off[4096] = sums[255];
}

__global__ void fill_k(const int* __restrict__ iout, const int* __restrict__ flag,
                       int* __restrict__ cur, int* __restrict__ ent) {
    int i = blockIdx.x * 256 + threadIdx.x;      // i = n*512 + o
    int c = iout[(size_t)i * flag[0]];
    int pos = atomicAdd(&cur[c], 1);
    ent[pos] = i;
}

// ---------- per-slab pipeline ----------

// xg[n][s_loc][j] = xT16[iin[n][j]][slab0 + s_loc]
template<int SLAB>
__global__ __launch_bounds__(256) void gather_k(
    const _Float16* __restrict__ xT16, const int* __restrict__ iin,
    const int* __restrict__ flag, int slab0, _Float16* __restrict__ xg)
{
    __shared__ _Float16 tile[64][264];
    __shared__ int cidx[64];
    const int t = threadIdx.x;
    const int j0 = blockIdx.x * 64;
    const int sb = blockIdx.y * 256;             // slab-local base (0 or 256)
    const int n = blockIdx.z;
    if (t < 64) cidx[t] = iin[((size_t)n * BIN + j0 + t) * flag[0]];
    __syncthreads();
    {
        int j = t >> 5, u = t & 31;
        #pragma unroll
        for (int p = 0; p < 8; ++p) {
            int jj = j + p * 8;
            half8 v = *(const half8*)(xT16 + (size_t)cidx[jj] * NROWS + slab0 + sb + u * 8);
            *(half8*)&tile[jj][u * 8] = v;
        }
    }
    __syncthreads();
    {
        int s = t >> 3, jj8 = (t & 7) * 8;
        #pragma unroll
        for (int p = 0; p < 8; ++p) {
            int ss = s + p * 32;
            half8 v;
            #pragma unroll
            for (int q = 0; q < 8; ++q) v[q] = tile[jj8 + q][ss];
            *(half8*)(xg + ((size_t)n * SLAB + sb + ss) * BIN + j0 + jj8) = v;
        }
    }
}

// dense GEMM: yb[n*512+o][s_loc] = sum_k xg[n][s_loc][k] * w16[n][o][k]
template<int SLAB>
__global__ __launch_bounds__(512) void gemm_dense_k(
    const _Float16* __restrict__ xg, const _Float16* __restrict__ w16,
    _Float16* __restrict__ yb)
{
    __shared__ __align__(1024) _Float16 As[2][128 * 32];   // 2 x 8 KiB
    __shared__ __align__(1024) _Float16 Bs[2][256 * 32];   // 2 x 16 KiB
    const int t = threadIdx.x;
    const int bid = blockIdx.x;
    const int MT = SLAB / 128;
    const int xcd = bid & 7;
    const int r = bid >> 3;
    const int mt = r % MT;
    const int ot = (r / MT) & 1;
    const int ng = r / (MT * 2);
    const int n = ng * 8 + xcd;                  // n == xcd (mod 8): W panel L2-resident
    const int s0 = mt * 128;                     // slab-local
    const int o0 = ot * 256;

    const int lane = t & 63, wid = t >> 6;
    char* Asb = (char*)As;
    char* Bsb = (char*)Bs;

    auto STAGE = [&](int buf, int k0) {
        {   // A: 128 rows x 64B from xg
            int s = t >> 2, sl = t & 3;
            const char* src = (const char*)(xg + ((size_t)n * SLAB + s0 + s) * BIN + k0)
                              + ((sl << 4) ^ (((s >> 1) & 3) << 4));
            gload16(src, Asb + buf * 8192 + (wid << 10));
        }
        #pragma unroll
        for (int j = 0; j < 2; ++j) {            // B: 256 rows x 64B from w16
            int sid = t + j * 512;
            int o = sid >> 2, sl = sid & 3;
            const char* src = (const char*)(w16 + ((size_t)n * BOUT + o0 + o) * BIN + k0)
                              + ((sl << 4) ^ (((o >> 1) & 3) << 4));
            gload16(src, Bsb + buf * 16384 + j * 8192 + (wid << 10));
        }
    };

    f32x4 acc[4][4];
    #pragma unroll
    for (int i = 0; i < 4; ++i)
        #pragma unroll
        for (int j = 0; j < 4; ++j) acc[i][j] = (f32x4){0.f, 0.f, 0.f, 0.f};

    STAGE(0, 0);
    __syncthreads();

    const int wr = wid >> 2, wc = wid & 3;       // 2 x 4 waves, 64(s) x 64(o)
    const int lr = lane & 15, lh = lane >> 4;

    for (int ks = 0; ks < 16; ++ks) {
        const int cur = ks & 1;
        if (ks < 15) STAGE(cur ^ 1, (ks + 1) * 32);
        half8 a[4], b[4];
        #pragma unroll
        for (int fm = 0; fm < 4; ++fm) {
            int srow = wr * 64 + fm * 16 + lr;
            a[fm] = *(const half8*)(Asb + cur * 8192 + srow * 64 +
                                    ((lh << 4) ^ (((srow >> 1) & 3) << 4)));
        }
        #pragma unroll
        for (int fn = 0; fn < 4; ++fn) {
            int orow = wc * 64 + fn * 16 + lr;
            b[fn] = *(const half8*)(Bsb + cur * 16384 + orow * 64 +
                                    ((lh << 4) ^ (((orow >> 1) & 3) << 4)));
        }
        #pragma unroll
        for (int fm = 0; fm < 4; ++fm)
            #pragma unroll
            for (int fn = 0; fn < 4; ++fn)
                acc[fm][fn] = __builtin_amdgcn_mfma_f32_16x16x32_f16(
                    a[fm], b[fn], acc[fm][fn], 0, 0, 0);
        __syncthreads();
    }

    // dense store: lane holds (col o = lr, rows s = lh*4 + 0..3) per fragment
    #pragma unroll
    for (int fm = 0; fm < 4; ++fm) {
        int s = s0 + wr * 64 + fm * 16 + lh * 4;
        #pragma unroll
        for (int fn = 0; fn < 4; ++fn) {
            int o = o0 + wc * 64 + fn * 16 + lr;
            half4 h;
            h[0] = (_Float16)acc[fm][fn][0]; h[1] = (_Float16)acc[fm][fn][1];
            h[2] = (_Float16)acc[fm][fn][2]; h[3] = (_Float16)acc[fm][fn][3];
            *(half4*)(yb + ((size_t)n * BOUT + o) * SLAB + s) = h;
        }
    }
}

// out[slab0+s][c] = bias[c] + sum_{(n,o) in inv[c]} yb[n*512+o][s]
template<int SLAB>
__global__ __launch_bounds__(256) void combine_k(
    const _Float16* __restrict__ yb, const float* __restrict__ bias,
    const int* __restrict__ off, const int* __restrict__ ent,
    int slab0, float* __restrict__ out)
{
    const int t = threadIdx.x;
    const int c = blockIdx.x * 16 + (t & 15);
    const int SW = SLAB / 16;                    // 32 or 16 s per thread
    const int sl0 = (t >> 4) * SW;
    float acc[32];
    #pragma unroll
    for (int j = 0; j < SW; ++j) acc[j] = 0.f;
    const int e0 = off[c], e1 = off[c + 1];
    for (int e = e0; e < e1; ++e) {
        int id = ent[e];
        const _Float16* p = yb + (size_t)id * SLAB + sl0;
        #pragma unroll
        for (int jv = 0; jv < SW / 8; ++jv) {
            half8 v = *(const half8*)(p + jv * 8);
            #pragma unroll
            for (int q = 0; q < 8; ++q) acc[jv * 8 + q] += (float)v[q];
        }
    }
    const float b = bias[c];
    #pragma unroll
    for (int j = 0; j < SW; ++j)
        out[(size_t)(slab0 + sl0 + j) * OUT_F + c] = acc[j] + b;
}

// ---------------- fallback path (tiny ws): direct atomics into out ----------------
__global__ void init_bias_k(const float* __restrict__ bias, float* __restrict__ out) {
    int i = blockIdx.x * blockDim.x + threadIdx.x;
    f32x4 b = *(const f32x4*)(bias + ((i & 1023) << 2));
    *(f32x4*)(out + (size_t)i * 4) = b;
}

__global__ __launch_bounds__(1024) void gemm_slow_k(
    const float* __restrict__ x, const float* __restrict__ w,
    const int* __restrict__ iin, const int* __restrict__ iout,
    const int* __restrict__ flag, float* __restrict__ out)
{
    __shared__ _Float16 As[128 * 32];
    __shared__ _Float16 Bs[512 * 32];
    __shared__ int kidx[BIN];
    __shared__ int oidx[BOUT];

    const int t = threadIdx.x;
    const int mt = blockIdx.x, n = blockIdx.y;
    const int m0 = mt * 128;
    const int stride = flag[0];

    if (t < BIN) kidx[t] = iin[(n * BIN + t) * stride];
    else         oidx[t - BIN] = iout[(n * BOUT + (t - BIN)) * stride];
    __syncthreads();

    const int lane = t & 63, wid = t >> 6;
    const int wr = wid >> 3, wc = wid & 7;
    const int lr = lane & 15, lh = lane >> 4;

    f32x4 acc[4][4];
    #pragma unroll
    for (int i = 0; i < 4; ++i)
        #pragma unroll
        for (int j = 0; j < 4; ++j) acc[i][j] = (f32x4){0.f, 0.f, 0.f, 0.f};

    char* Asb = (char*)As;
    char* Bsb = (char*)Bs;

    for (int k0 = 0; k0 < BIN; k0 += 32) {
        {
            int m = t >> 3, c4 = (t & 7) * 4;
            const float* xr = x + (size_t)(m0 + m) * IN_F;
            int i0 = kidx[k0 + c4], i1 = kidx[k0 + c4 + 1];
            int i2 = kidx[k0 + c4 + 2], i3 = kidx[k0 + c4 + 3];
            half4 p;
            p[0] = (_Float16)xr[i0]; p[1] = (_Float16)xr[i1];
            p[2] = (_Float16)xr[i2]; p[3] = (_Float16)xr[i3];
            *(half4*)(Asb + m * 64 + ((c4 * 2) ^ (((m >> 1) & 3) << 4))) = p;
        }
        {
            int o = t >> 1, h = t & 1;
            int sw = ((o >> 1) & 3) << 4;
            char* db = Bsb + o * 64;
            const float* src = w + ((size_t)n * BOUT + o) * BIN + k0 + h * 16;
            f32x4 a0 = *(const f32x4*)src;
            f32x4 a1 = *(const f32x4*)(src + 4);
            f32x4 a2 = *(const f32x4*)(src + 8);
            f32x4 a3 = *(const f32x4*)(src + 12);
            half8 p0, p1;
            p0[0] = (_Float16)a0[0]; p0[1] = (_Float16)a0[1];
            p0[2] = (_Float16)a0[2]; p0[3] = (_Float16)a0[3];
            p0[4] = (_Float16)a1[0]; p0[5] = (_Float16)a1[1];
            p0[6] = (_Float16)a1[2]; p0[7] = (_Float16)a1[3];
            p1[0] = (_Float16)a2[0]; p1[1] = (_Float16)a2[1];
            p1[2] = (_Float16)a2[2]; p1[3] = (_Float16)a2[3];
            p1[4] = (_Float16)a3[0]; p1[5] = (_Float16)a3[1];
            p1[6] = (_Float16)a3[2]; p1[7] = (_Float16)a3[3];
            *(half8*)(db + ((h * 32) ^ sw)) = p0;
            *(half8*)(db + ((h * 32 + 16) ^ sw)) = p1;
        }
        __syncthreads();
        {
            half8 a[4], b[4];
            #pragma unroll
            for (int fm = 0; fm < 4; ++fm) {
                int m = wr * 64 + fm * 16 + lr;
                a[fm] = *(const half8*)(Asb + m * 64 + ((lh * 16) ^ (((m >> 1) & 3) << 4)));
            }
            #pragma unroll
            for (int fn = 0; fn < 4; ++fn) {
                int o = wc * 64 + fn * 16 + lr;
                b[fn] = *(const half8*)(Bsb + o * 64 + ((lh * 16) ^ (((o >> 1) & 3) << 4)));
            }
            #pragma unroll
            for (int fm = 0; fm < 4; ++fm)
                #pragma unroll
                for (int fn = 0; fn < 4; ++fn)
                    acc[fm][fn] = __builtin_amdgcn_mfma_f32_16x16x32_f16(
                        a[fm], b[fn], acc[fm][fn], 0, 0, 0);
        }
        __syncthreads();
    }

    int ocol[4];
    #pragma unroll
    for (int fn = 0; fn < 4; ++fn) ocol[fn] = oidx[wc * 64 + fn * 16 + lr];
    #pragma unroll
    for (int fm = 0; fm < 4; ++fm) {
        int rbase = m0 + wr * 64 + fm * 16 + lh * 4;
        #pragma unroll
        for (int fn = 0; fn < 4; ++fn) {
            float* op = out + (size_t)rbase * OUT_F + ocol[fn];
            #pragma unroll
            for (int r = 0; r < 4; ++r)
                atomicAdd(op + (size_t)r * OUT_F, acc[fm][fn][r]);
        }
    }
}

// ---------------- host ----------------

template<int SLAB>
static void run_fast(const float* x, const float* w, const float* bias,
                     const int* iin, const int* iout, float* out,
                     char* ws, hipStream_t stream)
{
    const size_t MB = 1024u * 1024u;
    _Float16* w16  = (_Float16*)ws;                               // 32 MiB
    _Float16* xT16 = (_Float16*)(ws + 32 * MB);                   // 32 MiB
    _Float16* xg   = (_Float16*)(ws + 64 * MB);                   // SLAB*64*512*2
    const size_t xg_b = (size_t)SLAB * NBLK * BIN * 2;
    _Float16* yb   = (_Float16*)(ws + 64 * MB + xg_b);            // 64*512*SLAB*2
    const size_t yb_b = (size_t)NBLK * BOUT * SLAB * 2;
    char* meta = ws + 64 * MB + xg_b + yb_b;
    int* cnt  = (int*)meta;
    int* off  = cnt + 4096;
    int* cur  = off + 4097;
    int* ent  = cur + 4096;       // 32768
    int* flag = ent + NPAIR;

    detect_stride_k<<<1, 64, 0, stream>>>(iin, flag);
    cvt_w16_k<<<(NBLK * BOUT * BIN) / 1024, 256, 0, stream>>>(w, w16);
    transpose_x_k<<<dim3(IN_F / 64, NROWS / 64), 256, 0, stream>>>(x, xT16);
    hipMemsetAsync(cnt, 0, 4096 * sizeof(int), stream);
    count_k<<<NPAIR / 256, 256, 0, stream>>>(iout, flag, cnt);
    scan_k<<<1, 256, 0, stream>>>(cnt, off, cur);
    fill_k<<<NPAIR / 256, 256, 0, stream>>>(iout, flag, cur, ent);

    const int MT = SLAB / 128;
    for (int slab0 = 0; slab0 < NROWS; slab0 += SLAB) {
        gather_k<SLAB><<<dim3(BIN / 64, SLAB / 256, NBLK), 256, 0, stream>>>(
            xT16, iin, flag, slab0, xg);
        gemm_dense_k<SLAB><<<dim3(MT * 2 * NBLK), 512, 0, stream>>>(xg, w16, yb);
        combine_k<SLAB><<<dim3(OUT_F / 16), 256, 0, stream>>>(
            yb, bias, off, ent, slab0, out);
    }
}

extern "C" void kernel_launch(void* const* d_in, const int* in_sizes, int n_in,
                              void* d_out, int out_size, void* d_ws, size_t ws_size,
                              hipStream_t stream) {
    (void)in_sizes; (void)n_in; (void)out_size;
    const float* x    = (const float*)d_in[0];
    const float* w    = (const float*)d_in[1];
    const float* bias = (const float*)d_in[2];
    const int* iin    = (const int*)d_in[3];
    const int* iout   = (const int*)d_in[4];
    float* out        = (float*)d_out;

    const size_t MB = 1024u * 1024u;
    const size_t meta_b = (4096 + 4097 + 4096 + NPAIR + 64) * sizeof(int);
    const size_t needL = 64 * MB + 2 * ((size_t)512 * NBLK * BIN * 2) + meta_b; // ~128.2 MiB
    const size_t needM = 64 * MB + 2 * ((size_t)256 * NBLK * BIN * 2) + meta_b; // ~96.2 MiB

    if (ws_size >= needL) {
        run_fast<512>(x, w, bias, iin, iout, out, (char*)d_ws, stream);
    } else if (ws_size >= needM) {
        run_fast<256>(x, w, bias, iin, iout, out, (char*)d_ws, stream);
    } else {
        int* flag = (int*)d_ws;
        detect_stride_k<<<1, 64, 0, stream>>>(iin, flag);
        init_bias_k<<<(size_t)NROWS * OUT_F / 1024, 256, 0, stream>>>(bias, out);
        gemm_slow_k<<<dim3(NROWS / 128, NBLK), 1024, 0, stream>>>(
            x, w, iin, iout, flag, out);
    }
}

// Round 5
// 457.416 us; speedup vs baseline: 14.6820x; 1.2806x over previous
//
#include <hip/hip_runtime.h>

typedef _Float16 half8 __attribute__((ext_vector_type(8)));
typedef _Float16 half4 __attribute__((ext_vector_type(4)));
typedef float f32x4 __attribute__((ext_vector_type(4)));

#define IN_F 4096
#define OUT_F 4096
#define NROWS 4096   // B*S
#define NBLK 64
#define BIN 512
#define BOUT 512
#define NPAIR (NBLK * BOUT)   // 32768 (n,o) pairs

__device__ __forceinline__ void gload16(const void* g, void* l) {
    typedef __attribute__((address_space(1))) const void gvoid;
    typedef __attribute__((address_space(3))) void lvoid;
    __builtin_amdgcn_global_load_lds((gvoid*)g, (lvoid*)l, 16, 0, 0);
}

// ---------- setup kernels ----------

__global__ void detect_stride_k(const int* __restrict__ iin, int* __restrict__ flag) {
    int v = iin[threadIdx.x * 2 + 1];
    unsigned long long b = __ballot(v != 0);
    if (threadIdx.x == 0) flag[0] = (b == 0ULL) ? 2 : 1;
}

__global__ void cvt_w16_k(const float* __restrict__ w, _Float16* __restrict__ w16) {
    int i = (blockIdx.x * 256 + threadIdx.x) * 4;
    f32x4 v = *(const f32x4*)(w + i);
    half4 h;
    h[0] = (_Float16)v[0]; h[1] = (_Float16)v[1];
    h[2] = (_Float16)v[2]; h[3] = (_Float16)v[3];
    *(half4*)(w16 + i) = h;
}

// x[s][c] f32 -> xT16[c][s] f16
__global__ __launch_bounds__(256) void transpose_x_k(
    const float* __restrict__ x, _Float16* __restrict__ xT16)
{
    __shared__ float tile[64][65];
    const int c0 = blockIdx.x * 64, s0 = blockIdx.y * 64;
    const int t = threadIdx.x;
    {
        int s = t >> 4, c4 = (t & 15) * 4;
        #pragma unroll
        for (int p = 0; p < 4; ++p) {
            int ss = s + p * 16;
            f32x4 v = *(const f32x4*)(x + (size_t)(s0 + ss) * IN_F + c0 + c4);
            tile[ss][c4 + 0] = v[0]; tile[ss][c4 + 1] = v[1];
            tile[ss][c4 + 2] = v[2]; tile[ss][c4 + 3] = v[3];
        }
    }
    __syncthreads();
    {
        int c = t >> 3, s8 = (t & 7) * 8;
        #pragma unroll
        for (int p = 0; p < 2; ++p) {
            int cc = c + p * 32;
            half8 v;
            #pragma unroll
            for (int q = 0; q < 8; ++q) v[q] = (_Float16)tile[s8 + q][cc];
            *(half8*)(xT16 + (size_t)(c0 + cc) * NROWS + s0 + s8) = v;
        }
    }
}

// ---------- inverse-index build ----------

__global__ void count_k(const int* __restrict__ iout, const int* __restrict__ flag,
                        int* __restrict__ cnt) {
    int i = blockIdx.x * 256 + threadIdx.x;
    int c = iout[(size_t)i * flag[0]];
    atomicAdd(&cnt[c], 1);
}

__global__ __launch_bounds__(256) void scan_k(const int* __restrict__ cnt,
                                              int* __restrict__ off, int* __restrict__ cur) {
    __shared__ int sums[256];
    const int t = threadIdx.x;
    const int base = t * 16;
    int loc[16];
    int s = 0;
    #pragma unroll
    for (int i = 0; i < 16; ++i) { loc[i] = s; s += cnt[base + i]; }
    sums[t] = s;
    __syncthreads();
    for (int d = 1; d < 256; d <<= 1) {
        int v = (t >= d) ? sums[t - d] : 0;
        __syncthreads();
        sums[t] += v;
        __syncthreads();
    }
    int excl = sums[t] - s;
    #pragma unroll
    for (int i = 0; i < 16; ++i) {
        int o = excl + loc[i];
        off[base + i] = o;
        cur[base + i] = o;
    }
    if (t == 255) off[4096] = sums[255];
}

__global__ void fill_k(const int* __restrict__ iout, const int* __restrict__ flag,
                       int* __restrict__ cur, int* __restrict__ ent) {
    int i = blockIdx.x * 256 + threadIdx.x;
    int c = iout[(size_t)i * flag[0]];
    int pos = atomicAdd(&cur[c], 1);
    ent[pos] = i;
}

// ---------- per-slab pipeline ----------

// xg[n][s_loc][j] = xT16[iin[n][j]][slab0 + s_loc]
template<int SLAB>
__global__ __launch_bounds__(256) void gather_k(
    const _Float16* __restrict__ xT16, const int* __restrict__ iin,
    const int* __restrict__ flag, int slab0, _Float16* __restrict__ xg)
{
    __shared__ _Float16 tile[64][264];
    __shared__ int cidx[64];
    const int t = threadIdx.x;
    const int j0 = blockIdx.x * 64;
    const int sb = blockIdx.y * 256;
    const int n = blockIdx.z;
    if (t < 64) cidx[t] = iin[((size_t)n * BIN + j0 + t) * flag[0]];
    __syncthreads();
    {
        int j = t >> 5, u = t & 31;
        #pragma unroll
        for (int p = 0; p < 8; ++p) {
            int jj = j + p * 8;
            half8 v = *(const half8*)(xT16 + (size_t)cidx[jj] * NROWS + slab0 + sb + u * 8);
            *(half8*)&tile[jj][u * 8] = v;
        }
    }
    __syncthreads();
    {
        int s = t >> 3, jj8 = (t & 7) * 8;
        #pragma unroll
        for (int p = 0; p < 8; ++p) {
            int ss = s + p * 32;
            half8 v;
            #pragma unroll
            for (int q = 0; q < 8; ++q) v[q] = tile[jj8 + q][ss];
            *(half8*)(xg + ((size_t)n * SLAB + sb + ss) * BIN + j0 + jj8) = v;
        }
    }
}

// m97-structure dense GEMM: yb[n*512+o][s] = sum_k xg[n][s][k] * w16[n][o][k]
// 128x128 tile, BK=64, 4 waves, single-buffered 32 KiB LDS.
template<int SLAB>
__global__ __launch_bounds__(256) void gemm_dense_k(
    const _Float16* __restrict__ xg, const _Float16* __restrict__ w16,
    _Float16* __restrict__ yb)
{
    __shared__ __align__(1024) _Float16 As[128 * 64];   // 16 KiB
    __shared__ __align__(1024) _Float16 Bs[128 * 64];   // 16 KiB

    const int t = threadIdx.x;
    const int bid = blockIdx.x;
    constexpr int MT = SLAB / 128;              // s-tiles per n
    const int xcd = bid & 7;
    const int r = bid >> 3;
    const int mt = r % MT;
    const int ot = (r / MT) & 3;                // 4 o-tiles of 128
    const int ng = r / (MT * 4);
    const int n = ng * 8 + xcd;                 // n == xcd (mod 8): W panel L2-resident
    const int s0 = mt * 128;
    const int o0 = ot * 128;

    const int lane = t & 63, wid = t >> 6;      // 4 waves, 2x2, 64x64 each
    const int wr = wid >> 1, wc = wid & 1;
    const int lr = lane & 15, lh = lane >> 4;

    char* Asb = (char*)As;
    char* Bsb = (char*)Bs;

    f32x4 acc[4][4];
    #pragma unroll
    for (int i = 0; i < 4; ++i)
        #pragma unroll
        for (int j = 0; j < 4; ++j) acc[i][j] = (f32x4){0.f, 0.f, 0.f, 0.f};

    for (int ks = 0; ks < BIN / 64; ++ks) {
        const int k0 = ks * 64;
        // stage A: 128 rows x 128B (8 slots of 16B), XOR-swizzled source
        #pragma unroll
        for (int j = 0; j < 4; ++j) {
            int sid = t + j * 256;
            int row = sid >> 3, sl = sid & 7;
            const char* src = (const char*)(xg + ((size_t)n * SLAB + s0 + row) * BIN + k0)
                              + ((sl ^ (row & 7)) << 4);
            gload16(src, Asb + sid * 16);
        }
        // stage B: 128 rows x 128B from w16
        #pragma unroll
        for (int j = 0; j < 4; ++j) {
            int sid = t + j * 256;
            int row = sid >> 3, sl = sid & 7;
            const char* src = (const char*)(w16 + ((size_t)n * BOUT + o0 + row) * BIN + k0)
                              + ((sl ^ (row & 7)) << 4);
            gload16(src, Bsb + sid * 16);
        }
        __syncthreads();
        #pragma unroll
        for (int kk = 0; kk < 2; ++kk) {
            half8 a[4], b[4];
            #pragma unroll
            for (int fm = 0; fm < 4; ++fm) {
                int srow = wr * 64 + fm * 16 + lr;
                a[fm] = *(const half8*)(Asb + srow * 128 +
                                        (((kk * 4 + lh) ^ (srow & 7)) << 4));
            }
            #pragma unroll
            for (int fn = 0; fn < 4; ++fn) {
                int orow = wc * 64 + fn * 16 + lr;
                b[fn] = *(const half8*)(Bsb + orow * 128 +
                                        (((kk * 4 + lh) ^ (orow & 7)) << 4));
            }
            #pragma unroll
            for (int fm = 0; fm < 4; ++fm)
                #pragma unroll
                for (int fn = 0; fn < 4; ++fn)
                    acc[fm][fn] = __builtin_amdgcn_mfma_f32_16x16x32_f16(
                        a[fm], b[fn], acc[fm][fn], 0, 0, 0);
        }
        __syncthreads();
    }

    // store: s = s0+wr*64+fm*16+lh*4+reg (contig), o = o0+wc*64+fn*16+lr
    #pragma unroll
    for (int fm = 0; fm < 4; ++fm) {
        int s = s0 + wr * 64 + fm * 16 + lh * 4;
        #pragma unroll
        for (int fn = 0; fn < 4; ++fn) {
            int o = o0 + wc * 64 + fn * 16 + lr;
            half4 h;
            h[0] = (_Float16)acc[fm][fn][0]; h[1] = (_Float16)acc[fm][fn][1];
            h[2] = (_Float16)acc[fm][fn][2]; h[3] = (_Float16)acc[fm][fn][3];
            *(half4*)(yb + ((size_t)n * BOUT + o) * SLAB + s) = h;
        }
    }
}

// out[slab0+s][c] = bias[c] + sum_{(n,o) in inv[c]} yb[n*512+o][s]
template<int SLAB>
__global__ __launch_bounds__(256) void combine_k(
    const _Float16* __restrict__ yb, const float* __restrict__ bias,
    const int* __restrict__ off, const int* __restrict__ ent,
    int slab0, float* __restrict__ out)
{
    constexpr int SW = (SLAB >= 512) ? 32 : 16;
    const int t = threadIdx.x;
    const int c = blockIdx.x * 16 + (t & 15);
    const int sl0 = blockIdx.y * (16 * SW) + (t >> 4) * SW;
    float acc[SW];
    #pragma unroll
    for (int j = 0; j < SW; ++j) acc[j] = 0.f;
    const int e0 = off[c], e1 = off[c + 1];
    for (int e = e0; e < e1; ++e) {
        int id = ent[e];
        const _Float16* p = yb + (size_t)id * SLAB + sl0;
        #pragma unroll
        for (int jv = 0; jv < SW / 8; ++jv) {
            half8 v = *(const half8*)(p + jv * 8);
            #pragma unroll
            for (int q = 0; q < 8; ++q) acc[jv * 8 + q] += (float)v[q];
        }
    }
    const float b = bias[c];
    #pragma unroll
    for (int j = 0; j < SW; ++j)
        out[(size_t)(slab0 + sl0 + j) * OUT_F + c] = acc[j] + b;
}

// ---------------- fallback path (tiny ws): direct atomics into out ----------------
__global__ void init_bias_k(const float* __restrict__ bias, float* __restrict__ out) {
    int i = blockIdx.x * blockDim.x + threadIdx.x;
    f32x4 b = *(const f32x4*)(bias + ((i & 1023) << 2));
    *(f32x4*)(out + (size_t)i * 4) = b;
}

__global__ __launch_bounds__(1024) void gemm_slow_k(
    const float* __restrict__ x, const float* __restrict__ w,
    const int* __restrict__ iin, const int* __restrict__ iout,
    const int* __restrict__ flag, float* __restrict__ out)
{
    __shared__ _Float16 As[128 * 32];
    __shared__ _Float16 Bs[512 * 32];
    __shared__ int kidx[BIN];
    __shared__ int oidx[BOUT];

    const int t = threadIdx.x;
    const int mt = blockIdx.x, n = blockIdx.y;
    const int m0 = mt * 128;
    const int stride = flag[0];

    if (t < BIN) kidx[t] = iin[(n * BIN + t) * stride];
    else         oidx[t - BIN] = iout[(n * BOUT + (t - BIN)) * stride];
    __syncthreads();

    const int lane = t & 63, wid = t >> 6;
    const int wr = wid >> 3, wc = wid & 7;
    const int lr = lane & 15, lh = lane >> 4;

    f32x4 acc[4][4];
    #pragma unroll
    for (int i = 0; i < 4; ++i)
        #pragma unroll
        for (int j = 0; j < 4; ++j) acc[i][j] = (f32x4){0.f, 0.f, 0.f, 0.f};

    char* Asb = (char*)As;
    char* Bsb = (char*)Bs;

    for (int k0 = 0; k0 < BIN; k0 += 32) {
        {
            int m = t >> 3, c4 = (t & 7) * 4;
            const float* xr = x + (size_t)(m0 + m) * IN_F;
            int i0 = kidx[k0 + c4], i1 = kidx[k0 + c4 + 1];
            int i2 = kidx[k0 + c4 + 2], i3 = kidx[k0 + c4 + 3];
            half4 p;
            p[0] = (_Float16)xr[i0]; p[1] = (_Float16)xr[i1];
            p[2] = (_Float16)xr[i2]; p[3] = (_Float16)xr[i3];
            *(half4*)(Asb + m * 64 + ((c4 * 2) ^ (((m >> 1) & 3) << 4))) = p;
        }
        {
            int o = t >> 1, h = t & 1;
            int sw = ((o >> 1) & 3) << 4;
            char* db = Bsb + o * 64;
            const float* src = w + ((size_t)n * BOUT + o) * BIN + k0 + h * 16;
            f32x4 a0 = *(const f32x4*)src;
            f32x4 a1 = *(const f32x4*)(src + 4);
            f32x4 a2 = *(const f32x4*)(src + 8);
            f32x4 a3 = *(const f32x4*)(src + 12);
            half8 p0, p1;
            p0[0] = (_Float16)a0[0]; p0[1] = (_Float16)a0[1];
            p0[2] = (_Float16)a0[2]; p0[3] = (_Float16)a0[3];
            p0[4] = (_Float16)a1[0]; p0[5] = (_Float16)a1[1];
            p0[6] = (_Float16)a1[2]; p0[7] = (_Float16)a1[3];
            p1[0] = (_Float16)a2[0]; p1[1] = (_Float16)a2[1];
            p1[2] = (_Float16)a2[2]; p1[3] = (_Float16)a2[3];
            p1[4] = (_Float16)a3[0]; p1[5] = (_Float16)a3[1];
            p1[6] = (_Float16)a3[2]; p1[7] = (_Float16)a3[3];
            *(half8*)(db + ((h * 32) ^ sw)) = p0;
            *(half8*)(db + ((h * 32 + 16) ^ sw)) = p1;
        }
        __syncthreads();
        {
            half8 a[4], b[4];
            #pragma unroll
            for (int fm = 0; fm < 4; ++fm) {
                int m = wr * 64 + fm * 16 + lr;
                a[fm] = *(const half8*)(Asb + m * 64 + ((lh * 16) ^ (((m >> 1) & 3) << 4)));
            }
            #pragma unroll
            for (int fn = 0; fn < 4; ++fn) {
                int o = wc * 64 + fn * 16 + lr;
                b[fn] = *(const half8*)(Bsb + o * 64 + ((lh * 16) ^ (((o >> 1) & 3) << 4)));
            }
            #pragma unroll
            for (int fm = 0; fm < 4; ++fm)
                #pragma unroll
                for (int fn = 0; fn < 4; ++fn)
                    acc[fm][fn] = __builtin_amdgcn_mfma_f32_16x16x32_f16(
                        a[fm], b[fn], acc[fm][fn], 0, 0, 0);
        }
        __syncthreads();
    }

    int ocol[4];
    #pragma unroll
    for (int fn = 0; fn < 4; ++fn) ocol[fn] = oidx[wc * 64 + fn * 16 + lr];
    #pragma unroll
    for (int fm = 0; fm < 4; ++fm) {
        int rbase = m0 + wr * 64 + fm * 16 + lh * 4;
        #pragma unroll
        for (int fn = 0; fn < 4; ++fn) {
            float* op = out + (size_t)rbase * OUT_F + ocol[fn];
            #pragma unroll
            for (int r = 0; r < 4; ++r)
                atomicAdd(op + (size_t)r * OUT_F, acc[fm][fn][r]);
        }
    }
}

// ---------------- host ----------------

template<int SLAB>
static void run_fast(const float* x, const float* w, const float* bias,
                     const int* iin, const int* iout, float* out,
                     char* ws, hipStream_t stream)
{
    const size_t MB = 1024u * 1024u;
    _Float16* w16  = (_Float16*)ws;                               // 32 MiB
    _Float16* xT16 = (_Float16*)(ws + 32 * MB);                   // 32 MiB
    _Float16* xg   = (_Float16*)(ws + 64 * MB);
    const size_t xg_b = (size_t)SLAB * NBLK * BIN * 2;
    _Float16* yb   = (_Float16*)(ws + 64 * MB + xg_b);
    const size_t yb_b = (size_t)NBLK * BOUT * SLAB * 2;
    char* meta = ws + 64 * MB + xg_b + yb_b;
    int* cnt  = (int*)meta;
    int* off  = cnt + 4096;
    int* cur  = off + 4097;
    int* ent  = cur + 4096;
    int* flag = ent + NPAIR;

    detect_stride_k<<<1, 64, 0, stream>>>(iin, flag);
    cvt_w16_k<<<(NBLK * BOUT * BIN) / 1024, 256, 0, stream>>>(w, w16);
    transpose_x_k<<<dim3(IN_F / 64, NROWS / 64), 256, 0, stream>>>(x, xT16);
    hipMemsetAsync(cnt, 0, 4096 * sizeof(int), stream);
    count_k<<<NPAIR / 256, 256, 0, stream>>>(iout, flag, cnt);
    scan_k<<<1, 256, 0, stream>>>(cnt, off, cur);
    fill_k<<<NPAIR / 256, 256, 0, stream>>>(iout, flag, cur, ent);

    constexpr int MT = SLAB / 128;
    constexpr int SW = (SLAB >= 512) ? 32 : 16;
    for (int slab0 = 0; slab0 < NROWS; slab0 += SLAB) {
        gather_k<SLAB><<<dim3(BIN / 64, SLAB / 256, NBLK), 256, 0, stream>>>(
            xT16, iin, flag, slab0, xg);
        gemm_dense_k<SLAB><<<dim3(MT * 4 * NBLK), 256, 0, stream>>>(xg, w16, yb);
        combine_k<SLAB><<<dim3(OUT_F / 16, SLAB / (16 * SW)), 256, 0, stream>>>(
            yb, bias, off, ent, slab0, out);
    }
}

extern "C" void kernel_launch(void* const* d_in, const int* in_sizes, int n_in,
                              void* d_out, int out_size, void* d_ws, size_t ws_size,
                              hipStream_t stream) {
    (void)in_sizes; (void)n_in; (void)out_size;
    const float* x    = (const float*)d_in[0];
    const float* w    = (const float*)d_in[1];
    const float* bias = (const float*)d_in[2];
    const int* iin    = (const int*)d_in[3];
    const int* iout   = (const int*)d_in[4];
    float* out        = (float*)d_out;

    const size_t MB = 1024u * 1024u;
    const size_t meta_b = (4096 + 4097 + 4096 + NPAIR + 64) * sizeof(int);
    const size_t needXL = 64 * MB + 2 * ((size_t)1024 * NBLK * BIN * 2) + meta_b; // ~192.2 MiB
    const size_t needL  = 64 * MB + 2 * ((size_t)512  * NBLK * BIN * 2) + meta_b; // ~128.2 MiB
    const size_t needM  = 64 * MB + 2 * ((size_t)256  * NBLK * BIN * 2) + meta_b; // ~96.2 MiB

    if (ws_size >= needXL) {
        run_fast<1024>(x, w, bias, iin, iout, out, (char*)d_ws, stream);
    } else if (ws_size >= needL) {
        run_fast<512>(x, w, bias, iin, iout, out, (char*)d_ws, stream);
    } else if (ws_size >= needM) {
        run_fast<256>(x, w, bias, iin, iout, out, (char*)d_ws, stream);
    } else {
        int* flag = (int*)d_ws;
        detect_stride_k<<<1, 64, 0, stream>>>(iin, flag);
        init_bias_k<<<(size_t)NROWS * OUT_F / 1024, 256, 0, stream>>>(bias, out);
        gemm_slow_k<<<dim3(NROWS / 128, NBLK), 1024, 0, stream>>>(
            x, w, iin, iout, flag, out);
    }
}